// Round 2
// baseline (349.953 us; speedup 1.0000x reference)
//
#include <hip/hip_runtime.h>

// MultiHeadAttention: B=8, S=1024, HID=1024, NH=16, HD=64, fp32 in/out.
// Pipeline: convert x -> bf16; transpose weights -> bf16 NT; fused QKV GEMM
// (MFMA bf16, V written transposed); flash attention; projection GEMM (fp32 out).

using bf16x8 = __attribute__((ext_vector_type(8))) short;   // 8 bf16 in 4 VGPRs
using f32x4  = __attribute__((ext_vector_type(4))) float;

#define DEVFN __device__ __forceinline__

typedef const __attribute__((address_space(1))) void gas_void;
typedef __attribute__((address_space(3))) void las_void;

DEVFN void gload16(const void* g, void* l) {
  // async global->LDS, 16B per lane. LDS dest must be linear in lane order.
  __builtin_amdgcn_global_load_lds((gas_void*)g, (las_void*)l, 16, 0, 0);
}

DEVFN unsigned short f2bf(float f) {  // RNE float->bf16
  union { float f; unsigned u; } v; v.f = f;
  unsigned r = v.u + 0x7fffu + ((v.u >> 16) & 1u);
  return (unsigned short)(r >> 16);
}

// ---------------- convert x (fp32 -> bf16), 4 elems/thread ----------------
__global__ __launch_bounds__(256) void k_convert_x(const float* __restrict__ x,
                                                   unsigned short* __restrict__ xb) {
  int i = (blockIdx.x * 256 + threadIdx.x) * 4;
  float4 v = *reinterpret_cast<const float4*>(x + i);
  ushort4 o;
  o.x = f2bf(v.x); o.y = f2bf(v.y); o.z = f2bf(v.z); o.w = f2bf(v.w);
  *reinterpret_cast<ushort4*>(xb + i) = o;
}

// ------------- transpose+convert weights: W[k][n] -> Wt[n][k] bf16 -------------
// z = 0..2 -> Wq/Wk/Wv into Wcat (rows 0..3071); z = 3 -> Wp into Wpt.
__global__ __launch_bounds__(256) void k_transpose_w(const float* __restrict__ Wq,
                                                     const float* __restrict__ Wk,
                                                     const float* __restrict__ Wv,
                                                     const float* __restrict__ Wp,
                                                     unsigned short* __restrict__ Wcat,
                                                     unsigned short* __restrict__ Wpt) {
  __shared__ float tile[64][65];
  int z = blockIdx.z;
  const float* W = (z == 0) ? Wq : (z == 1) ? Wk : (z == 2) ? Wv : Wp;
  unsigned short* out = (z == 3) ? Wpt : (Wcat + (size_t)z * 1024 * 1024);
  int k0 = blockIdx.y * 64, n0 = blockIdx.x * 64;
  int t = threadIdx.x;
  int tr = t >> 4, tc = (t & 15) * 4;
#pragma unroll
  for (int p = 0; p < 4; ++p) {
    int k = p * 16 + tr;
    float4 v = *reinterpret_cast<const float4*>(W + (size_t)(k0 + k) * 1024 + n0 + tc);
    tile[k][tc + 0] = v.x; tile[k][tc + 1] = v.y;
    tile[k][tc + 2] = v.z; tile[k][tc + 3] = v.w;
  }
  __syncthreads();
#pragma unroll
  for (int p = 0; p < 4; ++p) {
    int n = p * 16 + tr;
    ushort4 o;
    o.x = f2bf(tile[tc + 0][n]); o.y = f2bf(tile[tc + 1][n]);
    o.z = f2bf(tile[tc + 2][n]); o.w = f2bf(tile[tc + 3][n]);
    *reinterpret_cast<ushort4*>(out + (size_t)(n0 + n) * 1024 + k0 + tc) = o;
  }
}

// ---------------- NT GEMM: C[M][N] = A[M][K] * Bt[N][K]^T, K=1024 ----------------
// 128x128 tile, BK=64, 4 waves (2x2), each wave 64x64 = 4x4 frags of 16x16x32.
// MODE 0: fused QKV epilogue (bf16; Q,K natural [m][n]; V transposed [b,h,d,s]).
// MODE 1: projection epilogue (fp32 + bias -> d_out).
template <int MODE>
__global__ __launch_bounds__(256) void k_gemm(const unsigned short* __restrict__ A,
                                              const unsigned short* __restrict__ Bt,
                                              const float* __restrict__ b0,
                                              const float* __restrict__ b1,
                                              const float* __restrict__ b2,
                                              unsigned short* __restrict__ Qb,
                                              unsigned short* __restrict__ Kb,
                                              unsigned short* __restrict__ Vtb,
                                              float* __restrict__ outp) {
  __shared__ unsigned short As[128 * 64];
  __shared__ unsigned short Bs[128 * 64];
  int t = threadIdx.x, lane = t & 63, w = t >> 6;
  int lgrp = lane >> 4, l16 = lane & 15;
  int n0 = blockIdx.x * 128, m0 = blockIdx.y * 128;
  int wm = w >> 1, wn = w & 1;
  const unsigned short* Ag = A + (size_t)m0 * 1024;
  const unsigned short* Bg = Bt + (size_t)n0 * 1024;

  const f32x4 zf = {0.f, 0.f, 0.f, 0.f};
  f32x4 acc[4][4];
#pragma unroll
  for (int mi = 0; mi < 4; ++mi)
#pragma unroll
    for (int ni = 0; ni < 4; ++ni) acc[mi][ni] = zf;

  for (int kt = 0; kt < 16; ++kt) {
    int kof = kt * 64;
#pragma unroll
    for (int is = 0; is < 4; ++is) {
      int ci = is * 256 + t;
      int row = ci >> 3, c = ci & 7;
      gload16(Ag + (size_t)row * 1024 + kof + c * 8, As + ci * 8);
      gload16(Bg + (size_t)row * 1024 + kof + c * 8, Bs + ci * 8);
    }
    __syncthreads();
    bf16x8 af[4][2], bfr[4][2];
#pragma unroll
    for (int mi = 0; mi < 4; ++mi)
#pragma unroll
      for (int s = 0; s < 2; ++s)
        af[mi][s] = *reinterpret_cast<const bf16x8*>(
            As + (wm * 64 + mi * 16 + l16) * 64 + s * 32 + lgrp * 8);
#pragma unroll
    for (int ni = 0; ni < 4; ++ni)
#pragma unroll
      for (int s = 0; s < 2; ++s)
        bfr[ni][s] = *reinterpret_cast<const bf16x8*>(
            Bs + (wn * 64 + ni * 16 + l16) * 64 + s * 32 + lgrp * 8);
#pragma unroll
    for (int mi = 0; mi < 4; ++mi)
#pragma unroll
      for (int ni = 0; ni < 4; ++ni)
#pragma unroll
        for (int s = 0; s < 2; ++s)
          acc[mi][ni] = __builtin_amdgcn_mfma_f32_16x16x32_bf16(
              af[mi][s], bfr[ni][s], acc[mi][ni], 0, 0, 0);
    __syncthreads();
  }

  if (MODE == 0) {
    int seg = n0 >> 10;        // 0=Q, 1=K, 2=V (uniform per block)
    int nn0 = n0 & 1023;
    const float* bias = (seg == 0) ? b0 : (seg == 1) ? b1 : b2;
#pragma unroll
    for (int ni = 0; ni < 4; ++ni) {
      int nl = wn * 64 + ni * 16 + l16;
      int n = nn0 + nl;
      float bval = bias[n];
#pragma unroll
      for (int mi = 0; mi < 4; ++mi) {
        int ml = wm * 64 + mi * 16 + lgrp * 4;
        if (seg < 2) {
          unsigned short* o = (seg == 0) ? Qb : Kb;
#pragma unroll
          for (int r = 0; r < 4; ++r)
            o[(size_t)(m0 + ml + r) * 1024 + n] = f2bf(acc[mi][ni][r] + bval);
        } else {
          int h = n >> 6, d = n & 63;
          int mg = m0 + ml;
          int bb = mg >> 10, s = mg & 1023;
          ushort4 o4;
          o4.x = f2bf(acc[mi][ni][0] + bval);
          o4.y = f2bf(acc[mi][ni][1] + bval);
          o4.z = f2bf(acc[mi][ni][2] + bval);
          o4.w = f2bf(acc[mi][ni][3] + bval);
          *reinterpret_cast<ushort4*>(Vtb + ((size_t)(bb * 16 + h) * 64 + d) * 1024 + s) = o4;
        }
      }
    }
  } else {
#pragma unroll
    for (int ni = 0; ni < 4; ++ni) {
      int n = n0 + wn * 64 + ni * 16 + l16;
      float bval = b0[n];
#pragma unroll
      for (int mi = 0; mi < 4; ++mi) {
        int ml = wm * 64 + mi * 16 + lgrp * 4;
#pragma unroll
        for (int r = 0; r < 4; ++r)
          outp[(size_t)(m0 + ml + r) * 1024 + n] = acc[mi][ni][r] + bval;
      }
    }
  }
}

// ---------------- flash attention ----------------
// grid (qt=16, bh=128), 256 threads = 4 waves; wave w owns q rows [w*16, w*16+16).
// K/Q/Vt LDS tiles XOR-swizzled (pre-swizzled global src, swizzled read) to kill
// the stride-128B 16-way bank conflict on ds_read_b128.
__global__ __launch_bounds__(256) void k_attn(const unsigned short* __restrict__ Qb,
                                              const unsigned short* __restrict__ Kb,
                                              const unsigned short* __restrict__ Vtb,
                                              const float* __restrict__ mask,
                                              unsigned short* __restrict__ ctx) {
  __shared__ unsigned short Qs[64 * 64];
  __shared__ unsigned short Ks[64 * 64];
  __shared__ unsigned short Vts[64 * 64];
  __shared__ unsigned short Ps[4][16 * 80];  // per-wave P, stride 80 (aligned, low-conflict)

  int t = threadIdx.x, lane = t & 63, w = t >> 6;
  int lgrp = lane >> 4, l16 = lane & 15;
  int qt = blockIdx.x, bh = blockIdx.y, b = bh >> 4, h = bh & 15;

  {  // stage Q tile (swizzled source -> linear LDS)
    const unsigned short* Qg = Qb + ((size_t)(b * 1024 + qt * 64)) * 1024 + h * 64;
#pragma unroll
    for (int is = 0; is < 2; ++is) {
      int ci = is * 256 + t, row = ci >> 3, c = ci & 7, cs = c ^ (row & 7);
      gload16(Qg + (size_t)row * 1024 + cs * 8, Qs + ci * 8);
    }
  }
  __syncthreads();
  bf16x8 aq[2];
  {
    int row = w * 16 + l16;
#pragma unroll
    for (int s = 0; s < 2; ++s) {
      int c = (s * 4 + lgrp) ^ (row & 7);
      aq[s] = *reinterpret_cast<const bf16x8*>(Qs + row * 64 + c * 8);
    }
  }

  const f32x4 zf = {0.f, 0.f, 0.f, 0.f};
  f32x4 acc[4];
#pragma unroll
  for (int dt = 0; dt < 4; ++dt) acc[dt] = zf;
  float m_r[4], l_r[4];
#pragma unroll
  for (int r = 0; r < 4; ++r) { m_r[r] = -__builtin_inff(); l_r[r] = 0.f; }

  const float* mrow = mask + (size_t)b * 1024 * 1024;
  int qg0 = qt * 64 + w * 16 + lgrp * 4;

  for (int kt = 0; kt < 16; ++kt) {
    const unsigned short* Kg = Kb + ((size_t)(b * 1024 + kt * 64)) * 1024 + h * 64;
    const unsigned short* Vg = Vtb + ((size_t)(b * 16 + h) * 64) * 1024 + kt * 64;
#pragma unroll
    for (int is = 0; is < 2; ++is) {
      int ci = is * 256 + t, row = ci >> 3, c = ci & 7, cs = c ^ (row & 7);
      gload16(Kg + (size_t)row * 1024 + cs * 8, Ks + ci * 8);
      gload16(Vg + (size_t)row * 1024 + cs * 8, Vts + ci * 8);
    }
    float mk[4][4];
#pragma unroll
    for (int ct = 0; ct < 4; ++ct)
#pragma unroll
      for (int r = 0; r < 4; ++r)
        mk[ct][r] = mrow[(size_t)(qg0 + r) * 1024 + kt * 64 + ct * 16 + l16];
    __syncthreads();

    // S = Q K^T (rows=q, cols=s_k)
    f32x4 sac[4];
#pragma unroll
    for (int ct = 0; ct < 4; ++ct) {
      sac[ct] = zf;
#pragma unroll
      for (int s = 0; s < 2; ++s) {
        int row = ct * 16 + l16;
        int c = (s * 4 + lgrp) ^ (row & 7);
        bf16x8 bk_ = *reinterpret_cast<const bf16x8*>(Ks + row * 64 + c * 8);
        sac[ct] = __builtin_amdgcn_mfma_f32_16x16x32_bf16(aq[s], bk_, sac[ct], 0, 0, 0);
      }
    }

    // scores: qk*scale + mask*(-1e9), separately rounded (match numpy, no FMA fuse)
    float pv[4][4], rmax[4];
#pragma unroll
    for (int r = 0; r < 4; ++r) {
      float mx = -__builtin_inff();
#pragma unroll
      for (int ct = 0; ct < 4; ++ct) {
        float sc = __fadd_rn(__fmul_rn(sac[ct][r], 0.03125f), __fmul_rn(mk[ct][r], -1e9f));
        pv[ct][r] = sc;
        mx = fmaxf(mx, sc);
      }
#pragma unroll
      for (int off = 1; off < 16; off <<= 1) mx = fmaxf(mx, __shfl_xor(mx, off));
      rmax[r] = mx;
    }
    float resc[4];
#pragma unroll
    for (int r = 0; r < 4; ++r) {
      float mn = fmaxf(m_r[r], rmax[r]);
      resc[r] = __expf(m_r[r] - mn);
      m_r[r] = mn;
    }
#pragma unroll
    for (int r = 0; r < 4; ++r) {
      float rs = 0.f;
#pragma unroll
      for (int ct = 0; ct < 4; ++ct) {
        float p = __expf(pv[ct][r] - m_r[r]);
        pv[ct][r] = p;
        rs += p;
      }
#pragma unroll
      for (int off = 1; off < 16; off <<= 1) rs += __shfl_xor(rs, off);
      l_r[r] = l_r[r] * resc[r] + rs;
    }
#pragma unroll
    for (int dt = 0; dt < 4; ++dt)
#pragma unroll
      for (int r = 0; r < 4; ++r) acc[dt][r] *= resc[r];

    // P (C-layout) -> LDS -> A-layout fragments
#pragma unroll
    for (int ct = 0; ct < 4; ++ct)
#pragma unroll
      for (int r = 0; r < 4; ++r)
        Ps[w][(lgrp * 4 + r) * 80 + ct * 16 + l16] = f2bf(pv[ct][r]);
    asm volatile("" ::: "memory");  // compiler fence: cross-lane LDS RAW in-wave

    // ctx += P * V  (B operand from V^T tile: contiguous in k)
#pragma unroll
    for (int s = 0; s < 2; ++s) {
      bf16x8 ap = *reinterpret_cast<const bf16x8*>(&Ps[w][l16 * 80 + s * 32 + lgrp * 8]);
#pragma unroll
      for (int dt = 0; dt < 4; ++dt) {
        int row = dt * 16 + l16;
        int c = (s * 4 + lgrp) ^ (row & 7);
        bf16x8 bv_ = *reinterpret_cast<const bf16x8*>(Vts + row * 64 + c * 8);
        acc[dt] = __builtin_amdgcn_mfma_f32_16x16x32_bf16(ap, bv_, acc[dt], 0, 0, 0);
      }
    }
    __syncthreads();  // protect Ks/Vts before next stage
  }

  // epilogue: ctx = acc / l -> bf16, layout [b, s, h, d] = [8192][1024]
#pragma unroll
  for (int dt = 0; dt < 4; ++dt)
#pragma unroll
    for (int r = 0; r < 4; ++r) {
      float v = acc[dt][r] / l_r[r];
      size_t m = (size_t)(b * 1024 + qt * 64 + w * 16 + lgrp * 4 + r);
      ctx[m * 1024 + h * 64 + dt * 16 + l16] = f2bf(v);
    }
}

// ---------------- launcher ----------------
extern "C" void kernel_launch(void* const* d_in, const int* in_sizes, int n_in,
                              void* d_out, int out_size, void* d_ws, size_t ws_size,
                              hipStream_t stream) {
  const float* x    = (const float*)d_in[0];
  const float* mask = (const float*)d_in[1];
  const float* Wq = (const float*)d_in[2];
  const float* bq = (const float*)d_in[3];
  const float* Wk = (const float*)d_in[4];
  const float* bk = (const float*)d_in[5];
  const float* Wv = (const float*)d_in[6];
  const float* bv = (const float*)d_in[7];
  const float* Wp = (const float*)d_in[8];
  const float* bp = (const float*)d_in[9];

  const size_t MB = 1u << 20;
  char* ws = (char*)d_ws;
  unsigned short* xbf  = (unsigned short*)(ws + 0);        // 16 MB [8192][1024]
  unsigned short* Wcat = (unsigned short*)(ws + 16 * MB);  // 6 MB  [3072][1024] (Wq^T|Wk^T|Wv^T)
  unsigned short* Wpt  = (unsigned short*)(ws + 22 * MB);  // 2 MB  [1024][1024]
  unsigned short* Qb   = (unsigned short*)(ws + 24 * MB);  // 16 MB [b,s,h,d]
  unsigned short* Kb   = (unsigned short*)(ws + 40 * MB);  // 16 MB [b,s,h,d]
  unsigned short* Vtb  = (unsigned short*)(ws + 56 * MB);  // 16 MB [b,h,d,s]
  unsigned short* ctx  = xbf;                              // reuse (x dead after QKV GEMM)

  k_convert_x<<<8192, 256, 0, stream>>>(x, xbf);
  k_transpose_w<<<dim3(16, 16, 4), 256, 0, stream>>>(Wq, Wk, Wv, Wp, Wcat, Wpt);
  k_gemm<0><<<dim3(24, 64), 256, 0, stream>>>(xbf, Wcat, bq, bk, bv, Qb, Kb, Vtb, nullptr);
  k_attn<<<dim3(16, 128), 256, 0, stream>>>(Qb, Kb, Vtb, mask, ctx);
  k_gemm<1><<<dim3(8, 64), 256, 0, stream>>>(ctx, Wpt, bp, nullptr, nullptr,
                                             nullptr, nullptr, nullptr, (float*)d_out);
}

// Round 3
// 342.044 us; speedup vs baseline: 1.0231x; 1.0231x over previous
//
#include <hip/hip_runtime.h>

// MultiHeadAttention: B=8, S=1024, HID=1024, NH=16, HD=64, fp32 in/out.
// Pipeline: convert x -> bf16; transpose weights -> bf16 NT; fused QKV GEMM
// (MFMA bf16, V transposed via LDS epilogue); flash attention (swapped QK^T,
// in-register softmax, 2-phase K/V double-buffer); projection GEMM (fp32 out).

using bf16x8 = __attribute__((ext_vector_type(8))) short;   // 8 bf16 in 4 VGPRs
using f32x4  = __attribute__((ext_vector_type(4))) float;

#define DEVFN __device__ __forceinline__

typedef const __attribute__((address_space(1))) void gas_void;
typedef __attribute__((address_space(3))) void las_void;

DEVFN void gload16(const void* g, void* l) {
  // async global->LDS, 16B per lane. LDS dest must be linear in lane order.
  __builtin_amdgcn_global_load_lds((gas_void*)g, (las_void*)l, 16, 0, 0);
}

DEVFN unsigned short f2bf(float f) {  // RNE float->bf16
  union { float f; unsigned u; } v; v.f = f;
  unsigned r = v.u + 0x7fffu + ((v.u >> 16) & 1u);
  return (unsigned short)(r >> 16);
}

DEVFN unsigned cvtpk(float lo, float hi) {  // 2xf32 -> packed 2xbf16 (HW RNE)
  unsigned r;
  asm("v_cvt_pk_bf16_f32 %0, %1, %2" : "=v"(r) : "v"(lo), "v"(hi));
  return r;
}

// ---------------- convert x (fp32 -> bf16), 4 elems/thread ----------------
__global__ __launch_bounds__(256) void k_convert_x(const float* __restrict__ x,
                                                   unsigned short* __restrict__ xb) {
  int i = (blockIdx.x * 256 + threadIdx.x) * 4;
  float4 v = *reinterpret_cast<const float4*>(x + i);
  ushort4 o;
  o.x = f2bf(v.x); o.y = f2bf(v.y); o.z = f2bf(v.z); o.w = f2bf(v.w);
  *reinterpret_cast<ushort4*>(xb + i) = o;
}

// ------------- transpose+convert weights: W[k][n] -> Wt[n][k] bf16 -------------
__global__ __launch_bounds__(256) void k_transpose_w(const float* __restrict__ Wq,
                                                     const float* __restrict__ Wk,
                                                     const float* __restrict__ Wv,
                                                     const float* __restrict__ Wp,
                                                     unsigned short* __restrict__ Wcat,
                                                     unsigned short* __restrict__ Wpt) {
  __shared__ float tile[64][65];
  int z = blockIdx.z;
  const float* W = (z == 0) ? Wq : (z == 1) ? Wk : (z == 2) ? Wv : Wp;
  unsigned short* out = (z == 3) ? Wpt : (Wcat + (size_t)z * 1024 * 1024);
  int k0 = blockIdx.y * 64, n0 = blockIdx.x * 64;
  int t = threadIdx.x;
  int tr = t >> 4, tc = (t & 15) * 4;
#pragma unroll
  for (int p = 0; p < 4; ++p) {
    int k = p * 16 + tr;
    float4 v = *reinterpret_cast<const float4*>(W + (size_t)(k0 + k) * 1024 + n0 + tc);
    tile[k][tc + 0] = v.x; tile[k][tc + 1] = v.y;
    tile[k][tc + 2] = v.z; tile[k][tc + 3] = v.w;
  }
  __syncthreads();
#pragma unroll
  for (int p = 0; p < 4; ++p) {
    int n = p * 16 + tr;
    ushort4 o;
    o.x = f2bf(tile[tc + 0][n]); o.y = f2bf(tile[tc + 1][n]);
    o.z = f2bf(tile[tc + 2][n]); o.w = f2bf(tile[tc + 3][n]);
    *reinterpret_cast<ushort4*>(out + (size_t)(n0 + n) * 1024 + k0 + tc) = o;
  }
}

// ---------------- NT GEMM: C[M][N] = A[M][K] * Bt[N][K]^T, K=1024 ----------------
// 128x128 tile, BK=64, 4 waves (2x2). MODE 0: fused QKV epilogue (bf16; Q,K
// natural [m][n]; V transposed via LDS -> [b,h,d,s] 16B stores). MODE 1: fp32+bias.
template <int MODE>
__global__ __launch_bounds__(256) void k_gemm(const unsigned short* __restrict__ A,
                                              const unsigned short* __restrict__ Bt,
                                              const float* __restrict__ b0,
                                              const float* __restrict__ b1,
                                              const float* __restrict__ b2,
                                              unsigned short* __restrict__ Qb,
                                              unsigned short* __restrict__ Kb,
                                              unsigned short* __restrict__ Vtb,
                                              float* __restrict__ outp) {
  __shared__ unsigned short sm[128 * 128];   // K-loop: As=sm[0:8K], Bs=sm[8K:16K]; epilogue: 128x128 transpose buf
  unsigned short* As = sm;
  unsigned short* Bs = sm + 128 * 64;
  int t = threadIdx.x, lane = t & 63, w = t >> 6;
  int lgrp = lane >> 4, l16 = lane & 15;
  int n0 = blockIdx.x * 128, m0 = blockIdx.y * 128;
  int wm = w >> 1, wn = w & 1;
  const unsigned short* Ag = A + (size_t)m0 * 1024;
  const unsigned short* Bg = Bt + (size_t)n0 * 1024;

  const f32x4 zf = {0.f, 0.f, 0.f, 0.f};
  f32x4 acc[4][4];
#pragma unroll
  for (int mi = 0; mi < 4; ++mi)
#pragma unroll
    for (int ni = 0; ni < 4; ++ni) acc[mi][ni] = zf;

  for (int kt = 0; kt < 16; ++kt) {
    int kof = kt * 64;
#pragma unroll
    for (int is = 0; is < 4; ++is) {
      int ci = is * 256 + t;
      int row = ci >> 3, c = ci & 7;
      gload16(Ag + (size_t)row * 1024 + kof + c * 8, As + ci * 8);
      gload16(Bg + (size_t)row * 1024 + kof + c * 8, Bs + ci * 8);
    }
    __syncthreads();
    bf16x8 af[4][2], bfr[4][2];
#pragma unroll
    for (int mi = 0; mi < 4; ++mi)
#pragma unroll
      for (int s = 0; s < 2; ++s)
        af[mi][s] = *reinterpret_cast<const bf16x8*>(
            As + (wm * 64 + mi * 16 + l16) * 64 + s * 32 + lgrp * 8);
#pragma unroll
    for (int ni = 0; ni < 4; ++ni)
#pragma unroll
      for (int s = 0; s < 2; ++s)
        bfr[ni][s] = *reinterpret_cast<const bf16x8*>(
            Bs + (wn * 64 + ni * 16 + l16) * 64 + s * 32 + lgrp * 8);
#pragma unroll
    for (int mi = 0; mi < 4; ++mi)
#pragma unroll
      for (int ni = 0; ni < 4; ++ni)
#pragma unroll
        for (int s = 0; s < 2; ++s)
          acc[mi][ni] = __builtin_amdgcn_mfma_f32_16x16x32_bf16(
              af[mi][s], bfr[ni][s], acc[mi][ni], 0, 0, 0);
    __syncthreads();
  }

  if (MODE == 0) {
    int seg = n0 >> 10;        // 0=Q, 1=K, 2=V (uniform per block)
    int nn0 = n0 & 1023;
    const float* bias = (seg == 0) ? b0 : (seg == 1) ? b1 : b2;
    if (seg < 2) {
      unsigned short* o = (seg == 0) ? Qb : Kb;
#pragma unroll
      for (int ni = 0; ni < 4; ++ni) {
        int n = nn0 + wn * 64 + ni * 16 + l16;
        float bval = bias[n];
#pragma unroll
        for (int mi = 0; mi < 4; ++mi) {
          int ml = wm * 64 + mi * 16 + lgrp * 4;
#pragma unroll
          for (int r = 0; r < 4; ++r)
            o[(size_t)(m0 + ml + r) * 1024 + n] = f2bf(acc[mi][ni][r] + bval);
        }
      }
    } else {
      // V: acc+bias -> LDS transposed [n][m] (XOR-swizzled), then coalesced 16B stores
#pragma unroll
      for (int ni = 0; ni < 4; ++ni) {
        int nl = wn * 64 + ni * 16 + l16;
        float bval = bias[nn0 + nl];
        int sw = (nl & 7) << 3;
#pragma unroll
        for (int mi = 0; mi < 4; ++mi) {
          int ml = wm * 64 + mi * 16 + lgrp * 4;
#pragma unroll
          for (int r = 0; r < 4; ++r)
            sm[nl * 128 + ((ml + r) ^ sw)] = f2bf(acc[mi][ni][r] + bval);
        }
      }
      __syncthreads();
      int bb = m0 >> 10, s0 = m0 & 1023;
      int nl = t >> 1, mh = (t & 1) * 64;
      int ng = nn0 + nl, hh = ng >> 6, d = ng & 63;
      unsigned short* vb = Vtb + ((size_t)(bb * 16 + hh) * 64 + d) * 1024 + s0;
      int sw = (nl & 7) << 3;
#pragma unroll
      for (int j = 0; j < 8; ++j) {
        int me = mh + j * 8;
        bf16x8 v = *reinterpret_cast<const bf16x8*>(sm + nl * 128 + (me ^ sw));
        *reinterpret_cast<bf16x8*>(vb + me) = v;
      }
    }
  } else {
#pragma unroll
    for (int ni = 0; ni < 4; ++ni) {
      int n = n0 + wn * 64 + ni * 16 + l16;
      float bval = b0[n];
#pragma unroll
      for (int mi = 0; mi < 4; ++mi) {
        int ml = wm * 64 + mi * 16 + lgrp * 4;
#pragma unroll
        for (int r = 0; r < 4; ++r)
          outp[(size_t)(m0 + ml + r) * 1024 + n] = acc[mi][ni][r] + bval;
      }
    }
  }
}

// ---------------- flash attention (swapped QK^T, dbuf K/V) ----------------
// 1D grid 2048 decoded so 16 h-blocks sharing a (b,qt) mask slice land on one XCD.
// 4 waves, wave w owns q rows w*16..w*16+15. Swapped S^T = mfma(K,Q): lane holds
// q=l16, k=ct*16+lgrp*4+r -> in-register row softmax (2 shuffles/reduce).
__global__ __launch_bounds__(256) void k_attn(const unsigned short* __restrict__ Qb,
                                              const unsigned short* __restrict__ Kb,
                                              const unsigned short* __restrict__ Vtb,
                                              const float* __restrict__ mask,
                                              unsigned short* __restrict__ ctx) {
  __shared__ unsigned short Qs[64 * 64];
  __shared__ unsigned short Ks[2][64 * 64];
  __shared__ unsigned short Vts[2][64 * 64];
  __shared__ unsigned short Ps[4][16 * 72];  // per-wave P [16 q][64 k], stride 72

  int t = threadIdx.x, lane = t & 63, w = t >> 6;
  int lgrp = lane >> 4, l16 = lane & 15;
  int gid = blockIdx.x;
  int xcd = gid & 7, ii = gid >> 3;
  int grp = (ii >> 4) * 8 + xcd;   // (b,qt) group: all 16 h-sharers on same XCD
  int h = ii & 15;
  int b = grp >> 4, qt = grp & 15;

  const unsigned short* Qg = Qb + ((size_t)(b * 1024 + qt * 64)) * 1024 + h * 64;
  const unsigned short* Kg = Kb + (size_t)b * 1024 * 1024 + h * 64;
  const unsigned short* Vg = Vtb + ((size_t)(b * 16 + h) * 64) * 1024;
  const float* mrow = mask + (size_t)b * 1024 * 1024 + (size_t)(qt * 64 + w * 16 + l16) * 1024;

  // prologue: stage Q, K0, V0 (swizzled src -> linear LDS); prefetch mask[0]
#pragma unroll
  for (int is = 0; is < 2; ++is) {
    int ci = is * 256 + t, row = ci >> 3, c = ci & 7, cs = c ^ (row & 7);
    gload16(Qg + (size_t)row * 1024 + cs * 8, Qs + ci * 8);
    gload16(Kg + (size_t)row * 1024 + cs * 8, Ks[0] + ci * 8);
    gload16(Vg + (size_t)row * 1024 + cs * 8, Vts[0] + ci * 8);
  }
  float4 mkc[4], mkn[4];
#pragma unroll
  for (int ct = 0; ct < 4; ++ct)
    mkc[ct] = *reinterpret_cast<const float4*>(mrow + ct * 16 + lgrp * 4);
  __syncthreads();

  bf16x8 aq[2];
  {
    int row = w * 16 + l16;
#pragma unroll
    for (int s = 0; s < 2; ++s) {
      int c = (s * 4 + lgrp) ^ (row & 7);
      aq[s] = *reinterpret_cast<const bf16x8*>(Qs + row * 64 + c * 8);
    }
  }

  const f32x4 zf = {0.f, 0.f, 0.f, 0.f};
  f32x4 acc[4];
#pragma unroll
  for (int dt = 0; dt < 4; ++dt) acc[dt] = zf;
  float m_s = -__builtin_inff(), l_s = 0.f;
  int cur = 0;

  for (int kt = 0; kt < 16; ++kt) {
    if (kt < 15) {  // prefetch next K/V tile + next mask; drained by end-of-iter barrier
#pragma unroll
      for (int is = 0; is < 2; ++is) {
        int ci = is * 256 + t, row = ci >> 3, c = ci & 7, cs = c ^ (row & 7);
        gload16(Kg + (size_t)(kt + 1) * 64 * 1024 + (size_t)row * 1024 + cs * 8,
                Ks[cur ^ 1] + ci * 8);
        gload16(Vg + (size_t)row * 1024 + (kt + 1) * 64 + cs * 8, Vts[cur ^ 1] + ci * 8);
      }
#pragma unroll
      for (int ct = 0; ct < 4; ++ct)
        mkn[ct] = *reinterpret_cast<const float4*>(mrow + (kt + 1) * 64 + ct * 16 + lgrp * 4);
    }

    // S^T = K Q^T: lane q=l16 (col), k=ct*16+lgrp*4+r (row); bit-identical to mfma(Q,K)
    float sc[16];
    float mx = -__builtin_inff();
#pragma unroll
    for (int ct = 0; ct < 4; ++ct) {
      f32x4 sac = zf;
#pragma unroll
      for (int s = 0; s < 2; ++s) {
        int row = ct * 16 + l16;
        int c = (s * 4 + lgrp) ^ (row & 7);
        bf16x8 ak = *reinterpret_cast<const bf16x8*>(Ks[cur] + row * 64 + c * 8);
        sac = __builtin_amdgcn_mfma_f32_16x16x32_bf16(ak, aq[s], sac, 0, 0, 0);
      }
      const float* mp = reinterpret_cast<const float*>(&mkc[ct]);
#pragma unroll
      for (int r = 0; r < 4; ++r) {
        // separately-rounded mul/add: must match numpy score ordering exactly
        float v = __fadd_rn(__fmul_rn(sac[r], 0.03125f), __fmul_rn(mp[r], -1e9f));
        sc[ct * 4 + r] = v;
        mx = fmaxf(mx, v);
      }
    }
    mx = fmaxf(mx, __shfl_xor(mx, 16, 64));
    mx = fmaxf(mx, __shfl_xor(mx, 32, 64));
    float mn = fmaxf(m_s, mx);
    float resc = __expf(m_s - mn);   // first iter: exp(-inf)=0
    m_s = mn;
    float rs = 0.f;
#pragma unroll
    for (int i = 0; i < 16; ++i) {
      float p = __expf(sc[i] - mn);
      sc[i] = p;
      rs += p;
    }
    rs += __shfl_xor(rs, 16, 64);
    rs += __shfl_xor(rs, 32, 64);
    l_s = l_s * resc + rs;

    // rescale acc: acc rows are q=lgrp*4+r; softmax state lives at lane l16=q
    float racc[4];
#pragma unroll
    for (int r = 0; r < 4; ++r) racc[r] = __shfl(resc, lgrp * 4 + r, 64);
#pragma unroll
    for (int dt = 0; dt < 4; ++dt)
#pragma unroll
      for (int r = 0; r < 4; ++r) acc[dt][r] *= racc[r];

    // P pack (HW cvt_pk) -> per-wave LDS [q][k], 8B stores of 4 consecutive k
#pragma unroll
    for (int ct = 0; ct < 4; ++ct) {
      uint2 u;
      u.x = cvtpk(sc[ct * 4 + 0], sc[ct * 4 + 1]);
      u.y = cvtpk(sc[ct * 4 + 2], sc[ct * 4 + 3]);
      *reinterpret_cast<uint2*>(&Ps[w][l16 * 72 + ct * 16 + lgrp * 4]) = u;
    }
    asm volatile("" ::: "memory");  // order in-wave LDS RAW

    // ctx += P * V  (A=P from Ps, B from V^T tile: contiguous in k)
#pragma unroll
    for (int s = 0; s < 2; ++s) {
      bf16x8 ap = *reinterpret_cast<const bf16x8*>(&Ps[w][l16 * 72 + s * 32 + lgrp * 8]);
#pragma unroll
      for (int dt = 0; dt < 4; ++dt) {
        int row = dt * 16 + l16;
        int c = (s * 4 + lgrp) ^ (row & 7);
        bf16x8 bv_ = *reinterpret_cast<const bf16x8*>(Vts[cur] + row * 64 + c * 8);
        acc[dt] = __builtin_amdgcn_mfma_f32_16x16x32_bf16(ap, bv_, acc[dt], 0, 0, 0);
      }
    }
    __syncthreads();  // drains prefetch vmcnt + protects LDS buffers
    cur ^= 1;
#pragma unroll
    for (int ct = 0; ct < 4; ++ct) mkc[ct] = mkn[ct];
  }

  // epilogue: ctx = acc / l -> bf16, layout [b, s, h, d]
  float linv[4];
#pragma unroll
  for (int r = 0; r < 4; ++r) linv[r] = 1.0f / __shfl(l_s, lgrp * 4 + r, 64);
  size_t mbase = (size_t)(b * 1024 + qt * 64 + w * 16 + lgrp * 4);
#pragma unroll
  for (int dt = 0; dt < 4; ++dt)
#pragma unroll
    for (int r = 0; r < 4; ++r)
      ctx[(mbase + r) * 1024 + h * 64 + dt * 16 + l16] = f2bf(acc[dt][r] * linv[r]);
}

// ---------------- launcher ----------------
extern "C" void kernel_launch(void* const* d_in, const int* in_sizes, int n_in,
                              void* d_out, int out_size, void* d_ws, size_t ws_size,
                              hipStream_t stream) {
  const float* x    = (const float*)d_in[0];
  const float* mask = (const float*)d_in[1];
  const float* Wq = (const float*)d_in[2];
  const float* bq = (const float*)d_in[3];
  const float* Wk = (const float*)d_in[4];
  const float* bk = (const float*)d_in[5];
  const float* Wv = (const float*)d_in[6];
  const float* bv = (const float*)d_in[7];
  const float* Wp = (const float*)d_in[8];
  const float* bp = (const float*)d_in[9];

  const size_t MB = 1u << 20;
  char* ws = (char*)d_ws;
  unsigned short* xbf  = (unsigned short*)(ws + 0);        // 16 MB [8192][1024]
  unsigned short* Wcat = (unsigned short*)(ws + 16 * MB);  // 6 MB  [3072][1024]
  unsigned short* Wpt  = (unsigned short*)(ws + 22 * MB);  // 2 MB  [1024][1024]
  unsigned short* Qb   = (unsigned short*)(ws + 24 * MB);  // 16 MB [b,s,h,d]
  unsigned short* Kb   = (unsigned short*)(ws + 40 * MB);  // 16 MB [b,s,h,d]
  unsigned short* Vtb  = (unsigned short*)(ws + 56 * MB);  // 16 MB [b,h,d,s]
  unsigned short* ctx  = xbf;                              // reuse (x dead after QKV GEMM)

  k_convert_x<<<8192, 256, 0, stream>>>(x, xbf);
  k_transpose_w<<<dim3(16, 16, 4), 256, 0, stream>>>(Wq, Wk, Wv, Wp, Wcat, Wpt);
  k_gemm<0><<<dim3(24, 64), 256, 0, stream>>>(xbf, Wcat, bq, bk, bv, Qb, Kb, Vtb, nullptr);
  k_attn<<<2048, 256, 0, stream>>>(Qb, Kb, Vtb, mask, ctx);
  k_gemm<1><<<dim3(8, 64), 256, 0, stream>>>(ctx, Wpt, bp, nullptr, nullptr,
                                             nullptr, nullptr, nullptr, (float*)d_out);
}

// Round 4
// 328.558 us; speedup vs baseline: 1.0651x; 1.0410x over previous
//
#include <hip/hip_runtime.h>

// MultiHeadAttention: B=8, S=1024, HID=1024, NH=16, HD=64, fp32 in/out.
// Pipeline: convert x -> bf16; transpose weights -> bf16 NT; fused QKV GEMM
// (MFMA bf16, V transposed via LDS epilogue); flash attention (swapped QK^T,
// in-register softmax, P aliased onto Q LDS, skip-rescale); projection GEMM.

using bf16x8 = __attribute__((ext_vector_type(8))) short;   // 8 bf16 in 4 VGPRs
using f32x4  = __attribute__((ext_vector_type(4))) float;

#define DEVFN __device__ __forceinline__

typedef const __attribute__((address_space(1))) void gas_void;
typedef __attribute__((address_space(3))) void las_void;

DEVFN void gload16(const void* g, void* l) {
  // async global->LDS, 16B per lane. LDS dest must be linear in lane order.
  __builtin_amdgcn_global_load_lds((gas_void*)g, (las_void*)l, 16, 0, 0);
}

DEVFN unsigned short f2bf(float f) {  // RNE float->bf16
  union { float f; unsigned u; } v; v.f = f;
  unsigned r = v.u + 0x7fffu + ((v.u >> 16) & 1u);
  return (unsigned short)(r >> 16);
}

DEVFN unsigned cvtpk(float lo, float hi) {  // 2xf32 -> packed 2xbf16 (HW RNE)
  unsigned r;
  asm("v_cvt_pk_bf16_f32 %0, %1, %2" : "=v"(r) : "v"(lo), "v"(hi));
  return r;
}

// ---------------- convert x (fp32 -> bf16), 4 elems/thread ----------------
__global__ __launch_bounds__(256) void k_convert_x(const float* __restrict__ x,
                                                   unsigned short* __restrict__ xb) {
  int i = (blockIdx.x * 256 + threadIdx.x) * 4;
  float4 v = *reinterpret_cast<const float4*>(x + i);
  ushort4 o;
  o.x = f2bf(v.x); o.y = f2bf(v.y); o.z = f2bf(v.z); o.w = f2bf(v.w);
  *reinterpret_cast<ushort4*>(xb + i) = o;
}

// ------------- transpose+convert weights: W[k][n] -> Wt[n][k] bf16 -------------
__global__ __launch_bounds__(256) void k_transpose_w(const float* __restrict__ Wq,
                                                     const float* __restrict__ Wk,
                                                     const float* __restrict__ Wv,
                                                     const float* __restrict__ Wp,
                                                     unsigned short* __restrict__ Wcat,
                                                     unsigned short* __restrict__ Wpt) {
  __shared__ float tile[64][65];
  int z = blockIdx.z;
  const float* W = (z == 0) ? Wq : (z == 1) ? Wk : (z == 2) ? Wv : Wp;
  unsigned short* out = (z == 3) ? Wpt : (Wcat + (size_t)z * 1024 * 1024);
  int k0 = blockIdx.y * 64, n0 = blockIdx.x * 64;
  int t = threadIdx.x;
  int tr = t >> 4, tc = (t & 15) * 4;
#pragma unroll
  for (int p = 0; p < 4; ++p) {
    int k = p * 16 + tr;
    float4 v = *reinterpret_cast<const float4*>(W + (size_t)(k0 + k) * 1024 + n0 + tc);
    tile[k][tc + 0] = v.x; tile[k][tc + 1] = v.y;
    tile[k][tc + 2] = v.z; tile[k][tc + 3] = v.w;
  }
  __syncthreads();
#pragma unroll
  for (int p = 0; p < 4; ++p) {
    int n = p * 16 + tr;
    ushort4 o;
    o.x = f2bf(tile[tc + 0][n]); o.y = f2bf(tile[tc + 1][n]);
    o.z = f2bf(tile[tc + 2][n]); o.w = f2bf(tile[tc + 3][n]);
    *reinterpret_cast<ushort4*>(out + (size_t)(n0 + n) * 1024 + k0 + tc) = o;
  }
}

// ---------------- NT GEMM: C[M][N] = A[M][K] * Bt[N][K]^T, K=1024 ----------------
// 128x128 tile, BK=64, 4 waves (2x2). MODE 0: fused QKV epilogue (bf16; Q,K
// natural [m][n]; V transposed via LDS -> [b,h,d,s] 16B stores). MODE 1: fp32+bias.
template <int MODE>
__global__ __launch_bounds__(256) void k_gemm(const unsigned short* __restrict__ A,
                                              const unsigned short* __restrict__ Bt,
                                              const float* __restrict__ b0,
                                              const float* __restrict__ b1,
                                              const float* __restrict__ b2,
                                              unsigned short* __restrict__ Qb,
                                              unsigned short* __restrict__ Kb,
                                              unsigned short* __restrict__ Vtb,
                                              float* __restrict__ outp) {
  __shared__ unsigned short sm[128 * 128];   // K-loop: As/Bs; epilogue: transpose buf
  unsigned short* As = sm;
  unsigned short* Bs = sm + 128 * 64;
  int t = threadIdx.x, lane = t & 63, w = t >> 6;
  int lgrp = lane >> 4, l16 = lane & 15;
  int n0 = blockIdx.x * 128, m0 = blockIdx.y * 128;
  int wm = w >> 1, wn = w & 1;
  const unsigned short* Ag = A + (size_t)m0 * 1024;
  const unsigned short* Bg = Bt + (size_t)n0 * 1024;

  const f32x4 zf = {0.f, 0.f, 0.f, 0.f};
  f32x4 acc[4][4];
#pragma unroll
  for (int mi = 0; mi < 4; ++mi)
#pragma unroll
    for (int ni = 0; ni < 4; ++ni) acc[mi][ni] = zf;

  for (int kt = 0; kt < 16; ++kt) {
    int kof = kt * 64;
#pragma unroll
    for (int is = 0; is < 4; ++is) {
      int ci = is * 256 + t;
      int row = ci >> 3, c = ci & 7;
      gload16(Ag + (size_t)row * 1024 + kof + c * 8, As + ci * 8);
      gload16(Bg + (size_t)row * 1024 + kof + c * 8, Bs + ci * 8);
    }
    __syncthreads();
    bf16x8 af[4][2], bfr[4][2];
#pragma unroll
    for (int mi = 0; mi < 4; ++mi)
#pragma unroll
      for (int s = 0; s < 2; ++s)
        af[mi][s] = *reinterpret_cast<const bf16x8*>(
            As + (wm * 64 + mi * 16 + l16) * 64 + s * 32 + lgrp * 8);
#pragma unroll
    for (int ni = 0; ni < 4; ++ni)
#pragma unroll
      for (int s = 0; s < 2; ++s)
        bfr[ni][s] = *reinterpret_cast<const bf16x8*>(
            Bs + (wn * 64 + ni * 16 + l16) * 64 + s * 32 + lgrp * 8);
#pragma unroll
    for (int mi = 0; mi < 4; ++mi)
#pragma unroll
      for (int ni = 0; ni < 4; ++ni)
#pragma unroll
        for (int s = 0; s < 2; ++s)
          acc[mi][ni] = __builtin_amdgcn_mfma_f32_16x16x32_bf16(
              af[mi][s], bfr[ni][s], acc[mi][ni], 0, 0, 0);
    __syncthreads();
  }

  if (MODE == 0) {
    int seg = n0 >> 10;        // 0=Q, 1=K, 2=V (uniform per block)
    int nn0 = n0 & 1023;
    const float* bias = (seg == 0) ? b0 : (seg == 1) ? b1 : b2;
    if (seg < 2) {
      unsigned short* o = (seg == 0) ? Qb : Kb;
#pragma unroll
      for (int ni = 0; ni < 4; ++ni) {
        int n = nn0 + wn * 64 + ni * 16 + l16;
        float bval = bias[n];
#pragma unroll
        for (int mi = 0; mi < 4; ++mi) {
          int ml = wm * 64 + mi * 16 + lgrp * 4;
#pragma unroll
          for (int r = 0; r < 4; ++r)
            o[(size_t)(m0 + ml + r) * 1024 + n] = f2bf(acc[mi][ni][r] + bval);
        }
      }
    } else {
      // V: acc+bias -> LDS transposed [n][m] (XOR-swizzled), then coalesced 16B stores
#pragma unroll
      for (int ni = 0; ni < 4; ++ni) {
        int nl = wn * 64 + ni * 16 + l16;
        float bval = bias[nn0 + nl];
        int sw = (nl & 7) << 3;
#pragma unroll
        for (int mi = 0; mi < 4; ++mi) {
          int ml = wm * 64 + mi * 16 + lgrp * 4;
#pragma unroll
          for (int r = 0; r < 4; ++r)
            sm[nl * 128 + ((ml + r) ^ sw)] = f2bf(acc[mi][ni][r] + bval);
        }
      }
      __syncthreads();
      int bb = m0 >> 10, s0 = m0 & 1023;
      int nl = t >> 1, mh = (t & 1) * 64;
      int ng = nn0 + nl, hh = ng >> 6, d = ng & 63;
      unsigned short* vb = Vtb + ((size_t)(bb * 16 + hh) * 64 + d) * 1024 + s0;
      int sw = (nl & 7) << 3;
#pragma unroll
      for (int j = 0; j < 8; ++j) {
        int me = mh + j * 8;
        bf16x8 v = *reinterpret_cast<const bf16x8*>(sm + nl * 128 + (me ^ sw));
        *reinterpret_cast<bf16x8*>(vb + me) = v;
      }
    }
  } else {
#pragma unroll
    for (int ni = 0; ni < 4; ++ni) {
      int n = n0 + wn * 64 + ni * 16 + l16;
      float bval = b0[n];
#pragma unroll
      for (int mi = 0; mi < 4; ++mi) {
        int ml = wm * 64 + mi * 16 + lgrp * 4;
#pragma unroll
        for (int r = 0; r < 4; ++r)
          outp[(size_t)(m0 + ml + r) * 1024 + n] = acc[mi][ni][r] + bval;
      }
    }
  }
}

// ---------------- flash attention (swapped QK^T, dbuf K/V, P aliased on Q) ----------------
// 1D grid 2048 decoded so 16 h-blocks sharing a (b,qt) mask slice land on one XCD.
// 4 waves, wave w owns q rows w*16..w*16+15. Swapped S^T = mfma(K,Q): lane holds
// q=l16, k=ct*16+lgrp*4+r -> in-register row softmax (2 shuffles/reduce).
// LDS 40 KB -> 4 blocks/CU.
__global__ __launch_bounds__(256) void k_attn(const unsigned short* __restrict__ Qb,
                                              const unsigned short* __restrict__ Kb,
                                              const unsigned short* __restrict__ Vtb,
                                              const float* __restrict__ mask,
                                              unsigned short* __restrict__ ctx) {
  __shared__ unsigned short QPs[64 * 64];   // prologue: Q tile; loop: P (XOR-swizzled)
  __shared__ unsigned short Ks[2][64 * 64];
  __shared__ unsigned short Vts[2][64 * 64];

  int t = threadIdx.x, lane = t & 63, w = t >> 6;
  int lgrp = lane >> 4, l16 = lane & 15;
  int gid = blockIdx.x;
  int xcd = gid & 7, ii = gid >> 3;
  int grp = (ii >> 4) * 8 + xcd;   // (b,qt) group: all 16 h-sharers on same XCD
  int h = ii & 15;
  int b = grp >> 4, qt = grp & 15;
  int row64 = w * 16 + l16;        // this lane's q row (both as softmax owner & P row)

  const unsigned short* Qg = Qb + ((size_t)(b * 1024 + qt * 64)) * 1024 + h * 64;
  const unsigned short* Kg = Kb + (size_t)b * 1024 * 1024 + h * 64;
  const unsigned short* Vg = Vtb + ((size_t)(b * 16 + h) * 64) * 1024;
  const float* mrow = mask + (size_t)b * 1024 * 1024 + (size_t)(qt * 64 + row64) * 1024;

  // prologue: stage Q, K0, V0 (swizzled src -> linear LDS); prefetch mask[0]
#pragma unroll
  for (int is = 0; is < 2; ++is) {
    int ci = is * 256 + t, row = ci >> 3, c = ci & 7, cs = c ^ (row & 7);
    gload16(Qg + (size_t)row * 1024 + cs * 8, QPs + ci * 8);
    gload16(Kg + (size_t)row * 1024 + cs * 8, Ks[0] + ci * 8);
    gload16(Vg + (size_t)row * 1024 + cs * 8, Vts[0] + ci * 8);
  }
  float4 mkc[4], mkn[4];
#pragma unroll
  for (int ct = 0; ct < 4; ++ct)
    mkc[ct] = *reinterpret_cast<const float4*>(mrow + ct * 16 + lgrp * 4);
  __syncthreads();

  bf16x8 aq[2];
#pragma unroll
  for (int s = 0; s < 2; ++s) {
    int c = (s * 4 + lgrp) ^ (row64 & 7);
    aq[s] = *reinterpret_cast<const bf16x8*>(QPs + row64 * 64 + c * 8);
  }
  __syncthreads();   // all waves have Q in regs; QPs becomes the P buffer

  const f32x4 zf = {0.f, 0.f, 0.f, 0.f};
  f32x4 acc[4];
#pragma unroll
  for (int dt = 0; dt < 4; ++dt) acc[dt] = zf;
  float m_s = -__builtin_inff(), l_s = 0.f;
  int cur = 0;

  for (int kt = 0; kt < 16; ++kt) {
    if (kt < 15) {  // prefetch next K/V tile + next mask; drained by end-of-iter barrier
#pragma unroll
      for (int is = 0; is < 2; ++is) {
        int ci = is * 256 + t, row = ci >> 3, c = ci & 7, cs = c ^ (row & 7);
        gload16(Kg + (size_t)(kt + 1) * 64 * 1024 + (size_t)row * 1024 + cs * 8,
                Ks[cur ^ 1] + ci * 8);
        gload16(Vg + (size_t)row * 1024 + (kt + 1) * 64 + cs * 8, Vts[cur ^ 1] + ci * 8);
      }
#pragma unroll
      for (int ct = 0; ct < 4; ++ct)
        mkn[ct] = *reinterpret_cast<const float4*>(mrow + (kt + 1) * 64 + ct * 16 + lgrp * 4);
    }

    // S^T = K Q^T: lane q=l16 (col), k=ct*16+lgrp*4+r (row); bit-identical to mfma(Q,K)
    float sc[16];
    float mx = -__builtin_inff();
    __builtin_amdgcn_s_setprio(1);
#pragma unroll
    for (int ct = 0; ct < 4; ++ct) {
      f32x4 sac = zf;
#pragma unroll
      for (int s = 0; s < 2; ++s) {
        int row = ct * 16 + l16;
        int c = (s * 4 + lgrp) ^ (row & 7);
        bf16x8 ak = *reinterpret_cast<const bf16x8*>(Ks[cur] + row * 64 + c * 8);
        sac = __builtin_amdgcn_mfma_f32_16x16x32_bf16(ak, aq[s], sac, 0, 0, 0);
      }
      const float* mp = reinterpret_cast<const float*>(&mkc[ct]);
#pragma unroll
      for (int r = 0; r < 4; ++r) {
        // separately-rounded mul/add: must match numpy score ordering exactly
        float v = __fadd_rn(__fmul_rn(sac[r], 0.03125f), __fmul_rn(mp[r], -1e9f));
        sc[ct * 4 + r] = v;
        mx = fmaxf(mx, v);
      }
    }
    __builtin_amdgcn_s_setprio(0);
    mx = fmaxf(mx, __shfl_xor(mx, 16, 64));
    mx = fmaxf(mx, __shfl_xor(mx, 32, 64));

    // skip-rescale (exact): if no q-row in this wave got a new max, resc == 1.
    bool skip = __all(mx <= m_s) != 0;
    float resc = 1.f;
    if (!skip) {
      float mn = fmaxf(m_s, mx);
      resc = __expf(m_s - mn);   // first iter: exp(-inf)=0
      m_s = mn;
    }
    float rs = 0.f;
#pragma unroll
    for (int i = 0; i < 16; ++i) {
      float p = __expf(sc[i] - m_s);
      sc[i] = p;
      rs += p;
    }
    rs += __shfl_xor(rs, 16, 64);
    rs += __shfl_xor(rs, 32, 64);
    if (skip) {
      l_s += rs;
    } else {
      l_s = l_s * resc + rs;
      // rescale acc: acc rows are q=lgrp*4+r; softmax state lives at lane l16=q
      float racc[4];
#pragma unroll
      for (int r = 0; r < 4; ++r) racc[r] = __shfl(resc, lgrp * 4 + r, 64);
#pragma unroll
      for (int dt = 0; dt < 4; ++dt)
#pragma unroll
        for (int r = 0; r < 4; ++r) acc[dt][r] *= racc[r];
    }

    // P pack (HW cvt_pk) -> QPs [row64][64] XOR-swizzled (16B-granule ^ (l16&7))
#pragma unroll
    for (int ct = 0; ct < 4; ++ct) {
      uint2 u;
      u.x = cvtpk(sc[ct * 4 + 0], sc[ct * 4 + 1]);
      u.y = cvtpk(sc[ct * 4 + 2], sc[ct * 4 + 3]);
      int chunk = ct * 2 + (lgrp >> 1);           // 16B granule within row
      int ep = row64 * 64 + ((chunk ^ (l16 & 7)) << 3) + ((lgrp & 1) << 2);
      *reinterpret_cast<uint2*>(&QPs[ep]) = u;
    }
    asm volatile("" ::: "memory");  // order in-wave LDS RAW

    // ctx += P * V  (A=P from QPs, B from V^T tile: contiguous in k)
    __builtin_amdgcn_s_setprio(1);
#pragma unroll
    for (int s = 0; s < 2; ++s) {
      int ec = row64 * 64 + (((s * 4 + lgrp) ^ (l16 & 7)) << 3);
      bf16x8 ap = *reinterpret_cast<const bf16x8*>(&QPs[ec]);
#pragma unroll
      for (int dt = 0; dt < 4; ++dt) {
        int row = dt * 16 + l16;
        int c = (s * 4 + lgrp) ^ (row & 7);
        bf16x8 bv_ = *reinterpret_cast<const bf16x8*>(Vts[cur] + row * 64 + c * 8);
        acc[dt] = __builtin_amdgcn_mfma_f32_16x16x32_bf16(ap, bv_, acc[dt], 0, 0, 0);
      }
    }
    __builtin_amdgcn_s_setprio(0);
    __syncthreads();  // drains prefetch vmcnt + protects LDS buffers
    cur ^= 1;
#pragma unroll
    for (int ct = 0; ct < 4; ++ct) mkc[ct] = mkn[ct];
  }

  // epilogue: ctx = acc / l -> bf16, layout [b, s, h, d]
  float linv[4];
#pragma unroll
  for (int r = 0; r < 4; ++r) linv[r] = 1.0f / __shfl(l_s, lgrp * 4 + r, 64);
  size_t mbase = (size_t)(b * 1024 + qt * 64 + w * 16 + lgrp * 4);
#pragma unroll
  for (int dt = 0; dt < 4; ++dt)
#pragma unroll
    for (int r = 0; r < 4; ++r)
      ctx[(mbase + r) * 1024 + h * 64 + dt * 16 + l16] = f2bf(acc[dt][r] * linv[r]);
}

// ---------------- launcher ----------------
extern "C" void kernel_launch(void* const* d_in, const int* in_sizes, int n_in,
                              void* d_out, int out_size, void* d_ws, size_t ws_size,
                              hipStream_t stream) {
  const float* x    = (const float*)d_in[0];
  const float* mask = (const float*)d_in[1];
  const float* Wq = (const float*)d_in[2];
  const float* bq = (const float*)d_in[3];
  const float* Wk = (const float*)d_in[4];
  const float* bk = (const float*)d_in[5];
  const float* Wv = (const float*)d_in[6];
  const float* bv = (const float*)d_in[7];
  const float* Wp = (const float*)d_in[8];
  const float* bp = (const float*)d_in[9];

  const size_t MB = 1u << 20;
  char* ws = (char*)d_ws;
  unsigned short* xbf  = (unsigned short*)(ws + 0);        // 16 MB [8192][1024]
  unsigned short* Wcat = (unsigned short*)(ws + 16 * MB);  // 6 MB  [3072][1024]
  unsigned short* Wpt  = (unsigned short*)(ws + 22 * MB);  // 2 MB  [1024][1024]
  unsigned short* Qb   = (unsigned short*)(ws + 24 * MB);  // 16 MB [b,s,h,d]
  unsigned short* Kb   = (unsigned short*)(ws + 40 * MB);  // 16 MB [b,s,h,d]
  unsigned short* Vtb  = (unsigned short*)(ws + 56 * MB);  // 16 MB [b,h,d,s]
  unsigned short* ctx  = xbf;                              // reuse (x dead after QKV GEMM)

  k_convert_x<<<8192, 256, 0, stream>>>(x, xbf);
  k_transpose_w<<<dim3(16, 16, 4), 256, 0, stream>>>(Wq, Wk, Wv, Wp, Wcat, Wpt);
  k_gemm<0><<<dim3(24, 64), 256, 0, stream>>>(xbf, Wcat, bq, bk, bv, Qb, Kb, Vtb, nullptr);
  k_attn<<<2048, 256, 0, stream>>>(Qb, Kb, Vtb, mask, ctx);
  k_gemm<1><<<dim3(8, 64), 256, 0, stream>>>(ctx, Wpt, bp, nullptr, nullptr,
                                             nullptr, nullptr, nullptr, (float*)d_out);
}